// Round 7
// baseline (584.796 us; speedup 1.0000x reference)
//
#include <hip/hip_runtime.h>
#include <hip/hip_bf16.h>

// ---------- types ----------
typedef float f32x4 __attribute__((ext_vector_type(4)));
typedef int   v8i   __attribute__((ext_vector_type(8)));
typedef __attribute__((address_space(3))) unsigned int       lds_uint;
typedef __attribute__((address_space(1))) const unsigned int glb_uint;

// ---------- helpers ----------
__device__ __forceinline__ float tanh_fast(float x) {
    float e = __expf(-2.0f * fabsf(x));
    float r = (1.0f - e) / (1.0f + e);
    return copysignf(r, x);
}
__device__ __forceinline__ unsigned char f2fp8(float v) {
    return (unsigned char)(__builtin_amdgcn_cvt_pk_fp8_f32(v, 0.0f, 0, false) & 0xff);
}

// ---------- prep: x->fp8; proj W ->fp8(x16) T; r1/r2 ->fp8(x16) T; bias concat ----------
__global__ __launch_bounds__(256) void prep(
    const float* __restrict__ x,
    const float* __restrict__ theta_w, const float* __restrict__ phi_w,
    const float* __restrict__ psi_w,   const float* __restrict__ r1_w,
    const float* __restrict__ r2_w,
    const float* __restrict__ theta_b, const float* __restrict__ phi_b,
    const float* __restrict__ psi_b,
    unsigned char* __restrict__ xb8, unsigned char* __restrict__ wCat8T,
    unsigned char* __restrict__ r1T8, unsigned char* __restrict__ r2T8,
    float* __restrict__ bCat) {
    const int b = blockIdx.x, t = threadIdx.x;
    if (b < 8192) {                       // cast x -> fp8
        long i = ((long)b * 256 + t) * 4;
        float4 f = *(const float4*)(x + i);
        int w = __builtin_amdgcn_cvt_pk_fp8_f32(f.x, f.y, 0, false);
        w = __builtin_amdgcn_cvt_pk_fp8_f32(f.z, f.w, w, true);
        *(unsigned int*)(xb8 + i) = (unsigned int)w;
    } else if (b < 11264) {               // proj weights (512x512 each), x16, transposed
        const int sel = (b - 8192) >> 10;
        const int idx = ((b - 8192) & 1023) * 256 + t;
        const float* w = sel == 0 ? theta_w : (sel == 1 ? phi_w : psi_w);
        const int r = idx >> 9, c = idx & 511;
        wCat8T[(long)(sel * 512 + c) * 512 + r] = f2fp8(w[idx] * 16.0f);
    } else if (b < 11776) {               // r1 (512x256) -> fp8 x16 T
        const int idx = (b - 11264) * 256 + t;
        const int r = idx >> 8, c = idx & 255;
        r1T8[(long)c * 512 + r] = f2fp8(r1_w[idx] * 16.0f);
    } else if (b < 12288) {               // r2 (256x512) -> fp8 x16 T
        const int idx = (b - 11776) * 256 + t;
        const int r = idx >> 9, c = idx & 511;
        r2T8[(long)c * 256 + r] = f2fp8(r2_w[idx] * 16.0f);
    } else {                              // bias concat (1536)
        const int i = (b - 12288) * 256 + t;
        if (i < 1536)
            bCat[i] = i < 512 ? theta_b[i] : (i < 1024 ? phi_b[i - 512] : psi_b[i - 1024]);
    }
}

// ---------- fp8 GEMM: 128x128 tile, BK=128, dbuf counted-vmcnt ----------
// MODE 0 proj:  v=acc/16+bCat[col]; col<1024 -> fp8 out8/out8b (pitch 512);
//               col>=1024 -> V^T (dword stores: 4 l-consecutive rows packed)
// MODE 3 r1:    v=acc/16+bias; leaky 0.2; fp8 -> out8, pitch 256
// MODE 4 r2:    v=acc/16+bias; tanh; +resid; fp32 -> outF, ldc 512
template <int MODE>
__global__ __launch_bounds__(256) void gemm_fp8(
    const unsigned char* __restrict__ A,
    const unsigned char* __restrict__ Bt,
    const float* __restrict__ bias,
    const float* __restrict__ resid,
    unsigned char* __restrict__ out8,
    unsigned char* __restrict__ out8b,
    unsigned char* __restrict__ outV,
    float* __restrict__ outF,
    int K, int ldaB, int ldbB, int ldc, long sA, long sB, long sC) {
    __shared__ unsigned char As[2][128 * 128];
    __shared__ unsigned char Bs[2][128 * 128];

    const int tid  = threadIdx.x;
    const int lane = tid & 63, wave = tid >> 6;
    const int m16  = lane & 15, quad = lane >> 4;
    const int wm   = (wave >> 1) << 6, wn = (wave & 1) << 6;
    const int m0   = blockIdx.x << 7, n0 = blockIdx.y << 7;

    const int srow = lane >> 3;
    const int uswz = (lane & 7) ^ srow;

    const unsigned char* Abase = A  + (long)blockIdx.z * sA + (long)m0 * ldaB;
    const unsigned char* Bbase = Bt + (long)blockIdx.z * sB + (long)n0 * ldbB;
    const int stR = (wave << 5) + srow;
    const long gA0 = (long)stR * ldaB + (uswz << 4);
    const long gB0 = (long)stR * ldbB + (uswz << 4);

    const int s8  = m16 & 7;
    const int P   = quad ^ (s8 >> 1);
    const int cLo = (P << 1) + (s8 & 1);
    const int offLo = cLo << 4;
    const int offHi = (cLo ^ 1) << 4;

    f32x4 acc[4][4] = {};
    union F8 { v8i v; int4 q[2]; };

    auto STAGE = [&](int buf, int kk) {
#pragma unroll
        for (int i = 0; i < 4; ++i) {
            const unsigned char* gp = Abase + gA0 + (long)(i << 3) * ldaB + kk;
            unsigned char* lp = &As[buf][((wave << 5) + (i << 3)) << 7];
            __builtin_amdgcn_global_load_lds((glb_uint*)gp, (lds_uint*)lp, 16, 0, 0);
        }
#pragma unroll
        for (int i = 0; i < 4; ++i) {
            const unsigned char* gp = Bbase + gB0 + (long)(i << 3) * ldbB + kk;
            unsigned char* lp = &Bs[buf][((wave << 5) + (i << 3)) << 7];
            __builtin_amdgcn_global_load_lds((glb_uint*)gp, (lds_uint*)lp, 16, 0, 0);
        }
    };

    STAGE(0, 0);
    int cur = 0;
    for (int k0 = 0; k0 < K; k0 += 128) {
        if (k0 + 128 < K) {
            STAGE(cur ^ 1, k0 + 128);
            asm volatile("s_waitcnt vmcnt(8)" ::: "memory");
        } else {
            asm volatile("s_waitcnt vmcnt(0)" ::: "memory");
        }
        asm volatile("s_barrier" ::: "memory");

        const unsigned char* Ab = As[cur];
        const unsigned char* Bb = Bs[cur];
        F8 af[4], bg[4];
#pragma unroll
        for (int f = 0; f < 4; ++f) {
            const int m = wm + (f << 4) + m16;
            const int n = wn + (f << 4) + m16;
            af[f].q[0] = *(const int4*)&Ab[(m << 7) + offLo];
            af[f].q[1] = *(const int4*)&Ab[(m << 7) + offHi];
            bg[f].q[0] = *(const int4*)&Bb[(n << 7) + offLo];
            bg[f].q[1] = *(const int4*)&Bb[(n << 7) + offHi];
        }
#pragma unroll
        for (int fi = 0; fi < 4; ++fi)
#pragma unroll
            for (int fj = 0; fj < 4; ++fj)
                acc[fi][fj] = __builtin_amdgcn_mfma_scale_f32_16x16x128_f8f6f4(
                    af[fi].v, bg[fj].v, acc[fi][fj],
                    0, 0, 0, 127, 0, 127);

        asm volatile("s_waitcnt lgkmcnt(0)" ::: "memory");
        asm volatile("s_barrier" ::: "memory");
        cur ^= 1;
    }

    if (MODE == 0) {
        const int sel = n0 >> 9;
        if (sel < 2) {
            unsigned char* dst = sel == 0 ? out8 : out8b;
#pragma unroll
            for (int fj = 0; fj < 4; ++fj) {
                const int col = n0 + wn + (fj << 4) + m16;
                const int cb  = col & 511;
                const float bv = bias[col];
#pragma unroll
                for (int fi = 0; fi < 4; ++fi)
#pragma unroll
                    for (int r = 0; r < 4; ++r) {
                        const int row = m0 + wm + (fi << 4) + (quad << 2) + r;
                        dst[(long)row * 512 + cb] = f2fp8(acc[fi][fj][r] * 0.0625f + bv);
                    }
            }
        } else {                                    // V^T: pack 4 l-rows per dword
            const int z = m0 >> 11, l0 = (m0 & 2047) + wm + (quad << 2);
#pragma unroll
            for (int fj = 0; fj < 4; ++fj) {
                const int col = n0 + wn + (fj << 4) + m16;
                const int h   = col & 511;
                const float bv = bias[col];
#pragma unroll
                for (int fi = 0; fi < 4; ++fi) {
                    int w = __builtin_amdgcn_cvt_pk_fp8_f32(
                        acc[fi][fj][0] * 0.0625f + bv, acc[fi][fj][1] * 0.0625f + bv, 0, false);
                    w = __builtin_amdgcn_cvt_pk_fp8_f32(
                        acc[fi][fj][2] * 0.0625f + bv, acc[fi][fj][3] * 0.0625f + bv, w, true);
                    *(unsigned int*)(outV + ((long)z * 512 + h) * 2048 + l0 + (fi << 4)) =
                        (unsigned int)w;
                }
            }
        }
    } else {
#pragma unroll
        for (int fj = 0; fj < 4; ++fj) {
            const int col = n0 + wn + (fj << 4) + m16;
            const float bv = bias[col];
#pragma unroll
            for (int fi = 0; fi < 4; ++fi)
#pragma unroll
                for (int r = 0; r < 4; ++r) {
                    const int row = m0 + wm + (fi << 4) + (quad << 2) + r;
                    float v = acc[fi][fj][r] * 0.0625f + bv;
                    if (MODE == 3) {
                        v = v > 0.0f ? v : 0.2f * v;
                        out8[(long)row * 256 + col] = f2fp8(v);
                    } else {
                        const long idx = (long)row * ldc + col;
                        outF[idx] = tanh_fast(v) + resid[idx];
                    }
                }
        }
    }
}

// ---------- flash v4: 32 q-rows/block, 2 blocks/CU, stage-AFTER-barrier (race-free) ----------
// 8 waves: S cols split by wave (16 keys each); PV h split by wave (16 h per quarter).
// All staging is issued immediately AFTER a barrier: once a wave passes barrier(ks),
// every wave's LDS reads from step ks-1 have retired (reads complete before each
// wave's own MFMA, which precedes its barrier arrival) -> WAR-safe.
// FIFO vmcnt (loads; 2/stage/thread), verified c=0/steady/c=15:
//   ks0: none (c>0; vmcnt(0) at c==0 for Q+Kt0)    queue after stages [Kt1,Vq0]
//   ks1: vmcnt(2) wait Kt1                         -> [Vq0,Kt2]
//   ks2: vmcnt(0) wait Kt2 (drains Vq0)            -> [Kt3]
//   ks3: vmcnt(0) wait Kt3; stage Vq1 then Kt0'    -> [Vq1,Kt0']
//   pre-q1: vmcnt(2) wait Vq1 (c<15; vmcnt(0) at c==15); stage Vq2
//   pre-q2: vmcnt(0) wait Vq2 (drains Kt0'); stage Vq3
//   pre-q3: vmcnt(0) wait Vq3
// LDS = Q 16K + K 2x16K + V 2x16K = 81920 B; P(4K)+sx/sy overlay the Ks1 window
// (tile3 reads retired by post-S barrier; next Ks1 write is stageK(c+1,1) after
// next chunk's ks0 barrier, with Ps/sy reads retired by pre-q1 barrier).
__global__ __launch_bounds__(512, 4) void flash(
    const unsigned char* __restrict__ Qg8,   // PH8 [8][2048][512]
    const unsigned char* __restrict__ Kg8,   // TH8 [8][2048][512]
    const unsigned char* __restrict__ Vg8,   // VT8 [8][512][2048]
    unsigned char* __restrict__ out8) {      // xadd [8][2048][512]
    __shared__ unsigned char lds[81920];
    unsigned char* Qs  = lds;                  // 16 KB
    unsigned char* Ks0 = lds + 16384;          // 16 KB (tiles 0,2 / next Kt0)
    unsigned char* Ks1 = lds + 32768;          // 16 KB (tiles 1,3; overlay below)
    unsigned char* Vs0 = lds + 49152;          // 16 KB (quarters 0,2)
    unsigned char* Vs1 = lds + 65536;          // 16 KB (quarters 1,3)
    unsigned char* Ps  = Ks1;                  // 4 KB  P (softmax..PV window)
    float* sx = (float*)(Ks1 + 4096);          // [32][8] row-max exchange
    float* sy = (float*)(Ks1 + 5120);          // [32][8] row-sum exchange

    const int tid  = threadIdx.x;
    const int lane = tid & 63, wave = tid >> 6;
    const int m16  = lane & 15, quad = lane >> 4;
    const int z    = blockIdx.y;
    const int l0   = blockIdx.x << 5;          // 32 q-rows / block

    const unsigned char* Qg = Qg8 + ((long)z * 2048 + l0) * 512;
    const unsigned char* Kg = Kg8 + (long)z * 2048 * 512;
    const unsigned char* Vg = Vg8 + (long)z * 512 * 2048;

    const int s8  = m16 & 7;
    const int cL  = ((quad ^ (s8 >> 1)) << 1) + (s8 & 1);
    const int offLo = cL << 4, offHi = (cL ^ 1) << 4;

    union F8 { v8i v; int4 q[2]; };

    auto stageQ = [&]() {                      // 32x512 once: 2 loads/thread
#pragma unroll
        for (int i = 0; i < 2; ++i) {
            const int slot = wave * 2 + i;     // 1KB seg = 2 rows
            const int row  = slot * 2 + (lane >> 5);
            const int u    = lane & 31;
            const int su   = (u & 24) | ((u & 7) ^ (row & 7));
            __builtin_amdgcn_global_load_lds(
                (glb_uint*)(Qg + (long)row * 512 + (su << 4)),
                (lds_uint*)(Qs + (slot << 10)), 16, 0, 0);
        }
    };
    auto stageK = [&](int c, int t) {          // 128 keys x 128B: 2 loads/thread
        unsigned char* base = (t & 1) ? Ks1 : Ks0;
#pragma unroll
        for (int i = 0; i < 2; ++i) {
            const int slot = wave * 2 + i;
            const int r    = (slot << 3) + (lane >> 3);
            const int su   = (lane & 7) ^ (r & 7);
            __builtin_amdgcn_global_load_lds(
                (glb_uint*)(Kg + (long)(c * 128 + r) * 512 + t * 128 + (su << 4)),
                (lds_uint*)(base + (slot << 10)), 16, 0, 0);
        }
    };
    auto stageV = [&](int c, int j) {          // 128 h-rows x 128B: 2 loads/thread
        unsigned char* base = (j & 1) ? Vs1 : Vs0;
#pragma unroll
        for (int i = 0; i < 2; ++i) {
            const int slot = wave * 2 + i;
            const int r    = (slot << 3) + (lane >> 3);
            const int su   = (lane & 7) ^ (r & 7);
            __builtin_amdgcn_global_load_lds(
                (glb_uint*)(Vg + (long)(j * 128 + r) * 2048 + c * 128 + (su << 4)),
                (lds_uint*)(base + (slot << 10)), 16, 0, 0);
        }
    };

    f32x4 U[2][4] = {};
    float m_run[2][4], l_run[2][4], alpha[2][4];
#pragma unroll
    for (int a = 0; a < 2; ++a)
#pragma unroll
        for (int b = 0; b < 4; ++b) { m_run[a][b] = -3.0e38f; l_run[a][b] = 0.0f; }

    stageQ();
    stageK(0, 0);

    for (int c = 0; c < 16; ++c) {
        f32x4 sacc[2] = {};
        // ---- S: 4 k-steps, 1 barrier each; staging AFTER the barrier ----
#pragma unroll
        for (int ks = 0; ks < 4; ++ks) {
            if (ks == 0) { if (c == 0) asm volatile("s_waitcnt vmcnt(0)" ::: "memory"); }
            else if (ks == 1) asm volatile("s_waitcnt vmcnt(2)" ::: "memory");
            else              asm volatile("s_waitcnt vmcnt(0)" ::: "memory");
            asm volatile("s_barrier" ::: "memory");
            if (ks == 0) { stageK(c, 1); stageV(c, 0); }
            else if (ks == 1) stageK(c, 2);
            else if (ks == 2) stageK(c, 3);
            else { stageV(c, 1); if (c + 1 < 16) stageK(c + 1, 0); }

            const unsigned char* Kb = (ks & 1) ? Ks1 : Ks0;
            F8 aq[2], bk;
#pragma unroll
            for (int fi = 0; fi < 2; ++fi) {
                const int l = fi * 16 + m16;
                aq[fi].q[0] = *(const int4*)&Qs[l * 512 + ks * 128 + offLo];
                aq[fi].q[1] = *(const int4*)&Qs[l * 512 + ks * 128 + offHi];
            }
            const int m = wave * 16 + m16;
            bk.q[0] = *(const int4*)&Kb[(m << 7) + offLo];
            bk.q[1] = *(const int4*)&Kb[(m << 7) + offHi];
            __builtin_amdgcn_s_setprio(1);
#pragma unroll
            for (int fi = 0; fi < 2; ++fi)
                sacc[fi] = __builtin_amdgcn_mfma_scale_f32_16x16x128_f8f6f4(
                    aq[fi].v, bk.v, sacc[fi], 0, 0, 0, 127, 0, 127);
            __builtin_amdgcn_s_setprio(0);
        }
        asm volatile("s_barrier" ::: "memory");   // post-S: all tile-3 reads retired

        // ---- softmax part 1: wave-local max (16 cols), cross-wave via sx ----
        float cm[2][4];
#pragma unroll
        for (int fi = 0; fi < 2; ++fi)
#pragma unroll
            for (int r = 0; r < 4; ++r) {
                float v = sacc[fi][r];
#pragma unroll
                for (int off = 1; off < 16; off <<= 1) v = fmaxf(v, __shfl_xor(v, off));
                cm[fi][r] = v;
            }
        if (m16 == 0) {
#pragma unroll
            for (int fi = 0; fi < 2; ++fi)
#pragma unroll
                for (int r = 0; r < 4; ++r)
                    sx[(fi * 16 + quad * 4 + r) * 8 + wave] = cm[fi][r];
        }
        asm volatile("s_waitcnt lgkmcnt(0)" ::: "memory");
        asm volatile("s_barrier" ::: "memory");

        // ---- softmax part 2: cm, T13 skip, p, sums, P publish ----
        bool grow = false;
#pragma unroll
        for (int fi = 0; fi < 2; ++fi)
#pragma unroll
            for (int r = 0; r < 4; ++r) {
                const int rr = fi * 16 + quad * 4 + r;
                float m1 = fmaxf(fmaxf(sx[rr * 8 + 0], sx[rr * 8 + 1]),
                                 fmaxf(sx[rr * 8 + 2], sx[rr * 8 + 3]));
                float m2 = fmaxf(fmaxf(sx[rr * 8 + 4], sx[rr * 8 + 5]),
                                 fmaxf(sx[rr * 8 + 6], sx[rr * 8 + 7]));
                cm[fi][r] = fmaxf(m1, m2);
                grow |= (cm[fi][r] > m_run[fi][r]);
            }
        if (__ballot(grow)) {
#pragma unroll
            for (int fi = 0; fi < 2; ++fi)
#pragma unroll
                for (int r = 0; r < 4; ++r) {
                    const float mn = fmaxf(m_run[fi][r], cm[fi][r]);
                    alpha[fi][r] = __expf(m_run[fi][r] - mn);
                    m_run[fi][r] = mn;
                }
#pragma unroll
            for (int fi = 0; fi < 2; ++fi)
#pragma unroll
                for (int j = 0; j < 4; ++j)
#pragma unroll
                    for (int r = 0; r < 4; ++r)
                        U[fi][j][r] *= alpha[fi][r];
        } else {
#pragma unroll
            for (int fi = 0; fi < 2; ++fi)
#pragma unroll
                for (int r = 0; r < 4; ++r) alpha[fi][r] = 1.0f;
        }
        float p[2][4];
#pragma unroll
        for (int fi = 0; fi < 2; ++fi)
#pragma unroll
            for (int r = 0; r < 4; ++r) {
                p[fi][r] = __expf(sacc[fi][r] - m_run[fi][r]);
                float v = p[fi][r];
#pragma unroll
                for (int off = 1; off < 16; off <<= 1) v += __shfl_xor(v, off);
                if (m16 == 0) sy[(fi * 16 + quad * 4 + r) * 8 + wave] = v;
            }
#pragma unroll
        for (int fi = 0; fi < 2; ++fi)
#pragma unroll
            for (int r = 0; r < 4; ++r) {
                const int l = fi * 16 + quad * 4 + r;
                Ps[(l << 7) + ((wave ^ (l & 7)) << 4) + m16] = f2fp8(p[fi][r] * 256.0f);
            }
        asm volatile("s_waitcnt lgkmcnt(0)" ::: "memory");
        asm volatile("s_barrier" ::: "memory");   // B: P/sy visible (Vq0 drained at ks2)

#pragma unroll
        for (int fi = 0; fi < 2; ++fi)
#pragma unroll
            for (int r = 0; r < 4; ++r) {
                const int rr = fi * 16 + quad * 4 + r;
                float s = ((sy[rr * 8 + 0] + sy[rr * 8 + 1]) + (sy[rr * 8 + 2] + sy[rr * 8 + 3]))
                        + ((sy[rr * 8 + 4] + sy[rr * 8 + 5]) + (sy[rr * 8 + 6] + sy[rr * 8 + 7]));
                l_run[fi][r] = l_run[fi][r] * alpha[fi][r] + s;
            }
        F8 pa[2];
#pragma unroll
        for (int fi = 0; fi < 2; ++fi) {
            const int l = fi * 16 + m16;
            pa[fi].q[0] = *(const int4*)&Ps[(l << 7) + offLo];
            pa[fi].q[1] = *(const int4*)&Ps[(l << 7) + offHi];
        }
        const int hl = wave * 16 + m16;
        // ---- quarter 0 (Vs0) ----
        {
            F8 vb;
            vb.q[0] = *(const int4*)&Vs0[(hl << 7) + offLo];
            vb.q[1] = *(const int4*)&Vs0[(hl << 7) + offHi];
            __builtin_amdgcn_s_setprio(1);
#pragma unroll
            for (int fi = 0; fi < 2; ++fi)
                U[fi][0] = __builtin_amdgcn_mfma_scale_f32_16x16x128_f8f6f4(
                    pa[fi].v, vb.v, U[fi][0], 0, 0, 0, 127, 0, 127);
            __builtin_amdgcn_s_setprio(0);
        }
        // ---- pre-q1: wait Vq1; barrier (q0 reads retired); stage Vq2 ----
        if (c + 1 < 16) asm volatile("s_waitcnt vmcnt(2)" ::: "memory");
        else            asm volatile("s_waitcnt vmcnt(0)" ::: "memory");
        asm volatile("s_barrier" ::: "memory");
        stageV(c, 2);
        {
            F8 vb;
            vb.q[0] = *(const int4*)&Vs1[(hl << 7) + offLo];
            vb.q[1] = *(const int4*)&Vs1[(hl << 7) + offHi];
            __builtin_amdgcn_s_setprio(1);
#pragma unroll
            for (int fi = 0; fi < 2; ++fi)
                U[fi][1] = __builtin_amdgcn_mfma_scale_f32_16x16x128_f8f6f4(
                    pa[fi].v, vb.v, U[fi][1], 0, 0, 0, 127, 0, 127);
            __builtin_amdgcn_s_setprio(0);
        }
        // ---- pre-q2: wait Vq2 (drains Kt0'); barrier; stage Vq3 ----
        asm volatile("s_waitcnt vmcnt(0)" ::: "memory");
        asm volatile("s_barrier" ::: "memory");
        stageV(c, 3);
        {
            F8 vb;
            vb.q[0] = *(const int4*)&Vs0[(hl << 7) + offLo];
            vb.q[1] = *(const int4*)&Vs0[(hl << 7) + offHi];
            __builtin_amdgcn_s_setprio(1);
#pragma unroll
            for (int fi = 0; fi < 2; ++fi)
                U[fi][2] = __builtin_amdgcn_mfma_scale_f32_16x16x128_f8f6f4(
                    pa[fi].v, vb.v, U[fi][2], 0, 0, 0, 127, 0, 127);
            __builtin_amdgcn_s_setprio(0);
        }
        // ---- pre-q3: wait Vq3; barrier ----
        asm volatile("s_waitcnt vmcnt(0)" ::: "memory");
        asm volatile("s_barrier" ::: "memory");
        {
            F8 vb;
            vb.q[0] = *(const int4*)&Vs1[(hl << 7) + offLo];
            vb.q[1] = *(const int4*)&Vs1[(hl << 7) + offHi];
            __builtin_amdgcn_s_setprio(1);
#pragma unroll
            for (int fi = 0; fi < 2; ++fi)
                U[fi][3] = __builtin_amdgcn_mfma_scale_f32_16x16x128_f8f6f4(
                    pa[fi].v, vb.v, U[fi][3], 0, 0, 0, 127, 0, 127);
            __builtin_amdgcn_s_setprio(0);
        }
    }

    // ---- epilogue: normalize, fp8 store ----
#pragma unroll
    for (int fi = 0; fi < 2; ++fi)
#pragma unroll
        for (int r = 0; r < 4; ++r) {
            const float inv = 1.0f / (256.0f * l_run[fi][r]);
            const long row = (long)z * 2048 + l0 + fi * 16 + quad * 4 + r;
#pragma unroll
            for (int j = 0; j < 4; ++j) {
                const int h = j * 128 + wave * 16 + m16;
                out8[row * 512 + h] = f2fp8(U[fi][j][r] * inv);
            }
        }
}

// ---------- launch ----------
extern "C" void kernel_launch(void* const* d_in, const int* in_sizes, int n_in,
                              void* d_out, int out_size, void* d_ws, size_t ws_size,
                              hipStream_t stream) {
    const float* x       = (const float*)d_in[0];
    const float* theta_w = (const float*)d_in[1];
    const float* theta_b = (const float*)d_in[2];
    const float* phi_w   = (const float*)d_in[3];
    const float* phi_b   = (const float*)d_in[4];
    const float* psi_w   = (const float*)d_in[5];
    const float* psi_b   = (const float*)d_in[6];
    const float* r1_w    = (const float*)d_in[7];
    const float* r1_b    = (const float*)d_in[8];
    const float* r2_w    = (const float*)d_in[9];
    const float* r2_b    = (const float*)d_in[10];
    float* out = (float*)d_out;

    constexpr int  N = 8, L = 2048, C = 512, H = 512, CH = 256;
    constexpr long NL = (long)N * L;  // 16384

    char* p = (char*)d_ws;
    auto alloc = [&](size_t bytes) { void* q = (void*)p; p += bytes; return q; };
    unsigned char*  xb8    = (unsigned char*)alloc(NL * C);            //  8 MB
    unsigned char*  TH8    = (unsigned char*)alloc(NL * H);            //  8 MB
    unsigned char*  PH8    = (unsigned char*)alloc(NL * H);            //  8 MB
    unsigned char*  VT8    = (unsigned char*)alloc((long)N * H * L);   //  8 MB
    unsigned char*  xadd8  = (unsigned char*)alloc(NL * H);            //  8 MB
    unsigned char*  h18    = (unsigned char*)alloc(NL * CH);           //  4 MB
    unsigned char*  wCat8T = (unsigned char*)alloc((long)1536 * 512);
    unsigned char*  r1T8   = (unsigned char*)alloc((long)H * CH);
    unsigned char*  r2T8   = (unsigned char*)alloc((long)CH * C);
    float*          bCat   = (float*)alloc(1536 * 4 + 256);

    // 1. prep
    prep<<<12294, 256, 0, stream>>>(x, theta_w, phi_w, psi_w, r1_w, r2_w,
                                    theta_b, phi_b, psi_b, xb8, wCat8T, r1T8, r2T8, bCat);

    // 2. merged fp8 projections -> TH8, PH8, VT8 (V^T via packed dword stores)
    gemm_fp8<0><<<dim3(NL / 128, 1536 / 128, 1), 256, 0, stream>>>(
        xb8, wCat8T, bCat, nullptr, TH8, PH8, VT8, nullptr,
        C, C, C, 0, 0, 0, 0);

    // 3-5. fused attention (32 q-rows/block, 2 blocks/CU, race-free schedule)
    flash<<<dim3(L / 32, N, 1), 512, 0, stream>>>(PH8, TH8, VT8, xadd8);

    // 6. h1 = leaky(x_add @ r1 + b) -> fp8
    gemm_fp8<3><<<dim3(NL / 128, CH / 128, 1), 256, 0, stream>>>(
        xadd8, r1T8, r1_b, nullptr, h18, nullptr, nullptr, nullptr,
        H, H, H, CH, 0, 0, 0);

    // 7. out = x + tanh(h1 @ r2 + b) -> fp32
    gemm_fp8<4><<<dim3(NL / 128, C / 128, 1), 256, 0, stream>>>(
        h18, r2T8, r2_b, x, nullptr, nullptr, nullptr, out,
        CH, CH, CH, C, 0, 0, 0);
}

// Round 8
// 366.312 us; speedup vs baseline: 1.5964x; 1.5964x over previous
//
#include <hip/hip_runtime.h>
#include <hip/hip_bf16.h>

// ---------- types ----------
typedef float f32x4 __attribute__((ext_vector_type(4)));
typedef int   v8i   __attribute__((ext_vector_type(8)));
typedef __attribute__((address_space(3))) unsigned int       lds_uint;
typedef __attribute__((address_space(1))) const unsigned int glb_uint;

// ---------- helpers ----------
__device__ __forceinline__ float tanh_fast(float x) {
    float e = __expf(-2.0f * fabsf(x));
    float r = (1.0f - e) / (1.0f + e);
    return copysignf(r, x);
}
__device__ __forceinline__ unsigned char f2fp8(float v) {
    return (unsigned char)(__builtin_amdgcn_cvt_pk_fp8_f32(v, 0.0f, 0, false) & 0xff);
}

// ---------- prep: x->fp8; proj W ->fp8(x16) T; r1/r2 ->fp8(x16) T; bias concat ----------
__global__ __launch_bounds__(256) void prep(
    const float* __restrict__ x,
    const float* __restrict__ theta_w, const float* __restrict__ phi_w,
    const float* __restrict__ psi_w,   const float* __restrict__ r1_w,
    const float* __restrict__ r2_w,
    const float* __restrict__ theta_b, const float* __restrict__ phi_b,
    const float* __restrict__ psi_b,
    unsigned char* __restrict__ xb8, unsigned char* __restrict__ wCat8T,
    unsigned char* __restrict__ r1T8, unsigned char* __restrict__ r2T8,
    float* __restrict__ bCat) {
    const int b = blockIdx.x, t = threadIdx.x;
    if (b < 8192) {                       // cast x -> fp8
        long i = ((long)b * 256 + t) * 4;
        float4 f = *(const float4*)(x + i);
        int w = __builtin_amdgcn_cvt_pk_fp8_f32(f.x, f.y, 0, false);
        w = __builtin_amdgcn_cvt_pk_fp8_f32(f.z, f.w, w, true);
        *(unsigned int*)(xb8 + i) = (unsigned int)w;
    } else if (b < 11264) {               // proj weights (512x512 each), x16, transposed
        const int sel = (b - 8192) >> 10;
        const int idx = ((b - 8192) & 1023) * 256 + t;
        const float* w = sel == 0 ? theta_w : (sel == 1 ? phi_w : psi_w);
        const int r = idx >> 9, c = idx & 511;
        wCat8T[(long)(sel * 512 + c) * 512 + r] = f2fp8(w[idx] * 16.0f);
    } else if (b < 11776) {               // r1 (512x256) -> fp8 x16 T
        const int idx = (b - 11264) * 256 + t;
        const int r = idx >> 8, c = idx & 255;
        r1T8[(long)c * 512 + r] = f2fp8(r1_w[idx] * 16.0f);
    } else if (b < 12288) {               // r2 (256x512) -> fp8 x16 T
        const int idx = (b - 11776) * 256 + t;
        const int r = idx >> 9, c = idx & 511;
        r2T8[(long)c * 256 + r] = f2fp8(r2_w[idx] * 16.0f);
    } else {                              // bias concat (1536)
        const int i = (b - 12288) * 256 + t;
        if (i < 1536)
            bCat[i] = i < 512 ? theta_b[i] : (i < 1024 ? phi_b[i - 512] : psi_b[i - 1024]);
    }
}

// ---------- fp8 GEMM: 128x128 tile, BK=128, dbuf counted-vmcnt ----------
// MODE 0 proj:  v=acc/16+bCat[col]; col<1024 -> fp8 out8/out8b (pitch 512);
//               col>=1024 -> V^T (dword stores: 4 l-consecutive rows packed)
// MODE 3 r1:    v=acc/16+bias; leaky 0.2; fp8 -> out8, pitch 256
// MODE 4 r2:    v=acc/16+bias; tanh; +resid; fp32 -> outF, ldc 512
template <int MODE>
__global__ __launch_bounds__(256) void gemm_fp8(
    const unsigned char* __restrict__ A,
    const unsigned char* __restrict__ Bt,
    const float* __restrict__ bias,
    const float* __restrict__ resid,
    unsigned char* __restrict__ out8,
    unsigned char* __restrict__ out8b,
    unsigned char* __restrict__ outV,
    float* __restrict__ outF,
    int K, int ldaB, int ldbB, int ldc, long sA, long sB, long sC) {
    __shared__ unsigned char As[2][128 * 128];
    __shared__ unsigned char Bs[2][128 * 128];

    const int tid  = threadIdx.x;
    const int lane = tid & 63, wave = tid >> 6;
    const int m16  = lane & 15, quad = lane >> 4;
    const int wm   = (wave >> 1) << 6, wn = (wave & 1) << 6;
    const int m0   = blockIdx.x << 7, n0 = blockIdx.y << 7;

    const int srow = lane >> 3;
    const int uswz = (lane & 7) ^ srow;

    const unsigned char* Abase = A  + (long)blockIdx.z * sA + (long)m0 * ldaB;
    const unsigned char* Bbase = Bt + (long)blockIdx.z * sB + (long)n0 * ldbB;
    const int stR = (wave << 5) + srow;
    const long gA0 = (long)stR * ldaB + (uswz << 4);
    const long gB0 = (long)stR * ldbB + (uswz << 4);

    const int s8  = m16 & 7;
    const int P   = quad ^ (s8 >> 1);
    const int cLo = (P << 1) + (s8 & 1);
    const int offLo = cLo << 4;
    const int offHi = (cLo ^ 1) << 4;

    f32x4 acc[4][4] = {};
    union F8 { v8i v; int4 q[2]; };

    auto STAGE = [&](int buf, int kk) {
#pragma unroll
        for (int i = 0; i < 4; ++i) {
            const unsigned char* gp = Abase + gA0 + (long)(i << 3) * ldaB + kk;
            unsigned char* lp = &As[buf][((wave << 5) + (i << 3)) << 7];
            __builtin_amdgcn_global_load_lds((glb_uint*)gp, (lds_uint*)lp, 16, 0, 0);
        }
#pragma unroll
        for (int i = 0; i < 4; ++i) {
            const unsigned char* gp = Bbase + gB0 + (long)(i << 3) * ldbB + kk;
            unsigned char* lp = &Bs[buf][((wave << 5) + (i << 3)) << 7];
            __builtin_amdgcn_global_load_lds((glb_uint*)gp, (lds_uint*)lp, 16, 0, 0);
        }
    };

    STAGE(0, 0);
    int cur = 0;
    for (int k0 = 0; k0 < K; k0 += 128) {
        if (k0 + 128 < K) {
            STAGE(cur ^ 1, k0 + 128);
            asm volatile("s_waitcnt vmcnt(8)" ::: "memory");
        } else {
            asm volatile("s_waitcnt vmcnt(0)" ::: "memory");
        }
        asm volatile("s_barrier" ::: "memory");

        const unsigned char* Ab = As[cur];
        const unsigned char* Bb = Bs[cur];
        F8 af[4], bg[4];
#pragma unroll
        for (int f = 0; f < 4; ++f) {
            const int m = wm + (f << 4) + m16;
            const int n = wn + (f << 4) + m16;
            af[f].q[0] = *(const int4*)&Ab[(m << 7) + offLo];
            af[f].q[1] = *(const int4*)&Ab[(m << 7) + offHi];
            bg[f].q[0] = *(const int4*)&Bb[(n << 7) + offLo];
            bg[f].q[1] = *(const int4*)&Bb[(n << 7) + offHi];
        }
#pragma unroll
        for (int fi = 0; fi < 4; ++fi)
#pragma unroll
            for (int fj = 0; fj < 4; ++fj)
                acc[fi][fj] = __builtin_amdgcn_mfma_scale_f32_16x16x128_f8f6f4(
                    af[fi].v, bg[fj].v, acc[fi][fj],
                    0, 0, 0, 127, 0, 127);

        asm volatile("s_waitcnt lgkmcnt(0)" ::: "memory");
        asm volatile("s_barrier" ::: "memory");
        cur ^= 1;
    }

    if (MODE == 0) {
        const int sel = n0 >> 9;
        if (sel < 2) {
            unsigned char* dst = sel == 0 ? out8 : out8b;
#pragma unroll
            for (int fj = 0; fj < 4; ++fj) {
                const int col = n0 + wn + (fj << 4) + m16;
                const int cb  = col & 511;
                const float bv = bias[col];
#pragma unroll
                for (int fi = 0; fi < 4; ++fi)
#pragma unroll
                    for (int r = 0; r < 4; ++r) {
                        const int row = m0 + wm + (fi << 4) + (quad << 2) + r;
                        dst[(long)row * 512 + cb] = f2fp8(acc[fi][fj][r] * 0.0625f + bv);
                    }
            }
        } else {                                    // V^T: pack 4 l-rows per dword
            const int z = m0 >> 11, l0 = (m0 & 2047) + wm + (quad << 2);
#pragma unroll
            for (int fj = 0; fj < 4; ++fj) {
                const int col = n0 + wn + (fj << 4) + m16;
                const int h   = col & 511;
                const float bv = bias[col];
#pragma unroll
                for (int fi = 0; fi < 4; ++fi) {
                    int w = __builtin_amdgcn_cvt_pk_fp8_f32(
                        acc[fi][fj][0] * 0.0625f + bv, acc[fi][fj][1] * 0.0625f + bv, 0, false);
                    w = __builtin_amdgcn_cvt_pk_fp8_f32(
                        acc[fi][fj][2] * 0.0625f + bv, acc[fi][fj][3] * 0.0625f + bv, w, true);
                    *(unsigned int*)(outV + ((long)z * 512 + h) * 2048 + l0 + (fi << 4)) =
                        (unsigned int)w;
                }
            }
        }
    } else {
#pragma unroll
        for (int fj = 0; fj < 4; ++fj) {
            const int col = n0 + wn + (fj << 4) + m16;
            const float bv = bias[col];
#pragma unroll
            for (int fi = 0; fi < 4; ++fi)
#pragma unroll
                for (int r = 0; r < 4; ++r) {
                    const int row = m0 + wm + (fi << 4) + (quad << 2) + r;
                    float v = acc[fi][fj][r] * 0.0625f + bv;
                    if (MODE == 3) {
                        v = v > 0.0f ? v : 0.2f * v;
                        out8[(long)row * 256 + col] = f2fp8(v);
                    } else {
                        const long idx = (long)row * ldc + col;
                        outF[idx] = tanh_fast(v) + resid[idx];
                    }
                }
        }
    }
}

// ---------- flash v5: v4 schedule (race-free, verified) with spill-free regalloc ----------
// ONLY change vs v4: __launch_bounds__(512) (no min-waves arg). v4's (512,4) made
// the backend cap VGPR at 64 -> ~870 MB scratch spill traffic (WRITE_SIZE counter).
// Plain (512) allocates 128 VGPR (measured round-4) -> 4 waves/SIMD; with LDS
// 81920 both limits land on 2 blocks/CU (the co-tenancy target).
// Schedule (verified correct, absmax 0.0703):
//   stage-AFTER-barrier (WAR-safe); FIFO vmcnt per issue point; P/sx/sy overlay Ks1.
__global__ __launch_bounds__(512) void flash(
    const unsigned char* __restrict__ Qg8,   // PH8 [8][2048][512]
    const unsigned char* __restrict__ Kg8,   // TH8 [8][2048][512]
    const unsigned char* __restrict__ Vg8,   // VT8 [8][512][2048]
    unsigned char* __restrict__ out8) {      // xadd [8][2048][512]
    __shared__ unsigned char lds[81920];
    unsigned char* Qs  = lds;                  // 16 KB
    unsigned char* Ks0 = lds + 16384;          // 16 KB (tiles 0,2 / next Kt0)
    unsigned char* Ks1 = lds + 32768;          // 16 KB (tiles 1,3; overlay below)
    unsigned char* Vs0 = lds + 49152;          // 16 KB (quarters 0,2)
    unsigned char* Vs1 = lds + 65536;          // 16 KB (quarters 1,3)
    unsigned char* Ps  = Ks1;                  // 4 KB  P (softmax..PV window)
    float* sx = (float*)(Ks1 + 4096);          // [32][8] row-max exchange
    float* sy = (float*)(Ks1 + 5120);          // [32][8] row-sum exchange

    const int tid  = threadIdx.x;
    const int lane = tid & 63, wave = tid >> 6;
    const int m16  = lane & 15, quad = lane >> 4;
    const int z    = blockIdx.y;
    const int l0   = blockIdx.x << 5;          // 32 q-rows / block

    const unsigned char* Qg = Qg8 + ((long)z * 2048 + l0) * 512;
    const unsigned char* Kg = Kg8 + (long)z * 2048 * 512;
    const unsigned char* Vg = Vg8 + (long)z * 512 * 2048;

    const int s8  = m16 & 7;
    const int cL  = ((quad ^ (s8 >> 1)) << 1) + (s8 & 1);
    const int offLo = cL << 4, offHi = (cL ^ 1) << 4;

    union F8 { v8i v; int4 q[2]; };

    auto stageQ = [&]() {                      // 32x512 once: 2 loads/thread
#pragma unroll
        for (int i = 0; i < 2; ++i) {
            const int slot = wave * 2 + i;     // 1KB seg = 2 rows
            const int row  = slot * 2 + (lane >> 5);
            const int u    = lane & 31;
            const int su   = (u & 24) | ((u & 7) ^ (row & 7));
            __builtin_amdgcn_global_load_lds(
                (glb_uint*)(Qg + (long)row * 512 + (su << 4)),
                (lds_uint*)(Qs + (slot << 10)), 16, 0, 0);
        }
    };
    auto stageK = [&](int c, int t) {          // 128 keys x 128B: 2 loads/thread
        unsigned char* base = (t & 1) ? Ks1 : Ks0;
#pragma unroll
        for (int i = 0; i < 2; ++i) {
            const int slot = wave * 2 + i;
            const int r    = (slot << 3) + (lane >> 3);
            const int su   = (lane & 7) ^ (r & 7);
            __builtin_amdgcn_global_load_lds(
                (glb_uint*)(Kg + (long)(c * 128 + r) * 512 + t * 128 + (su << 4)),
                (lds_uint*)(base + (slot << 10)), 16, 0, 0);
        }
    };
    auto stageV = [&](int c, int j) {          // 128 h-rows x 128B: 2 loads/thread
        unsigned char* base = (j & 1) ? Vs1 : Vs0;
#pragma unroll
        for (int i = 0; i < 2; ++i) {
            const int slot = wave * 2 + i;
            const int r    = (slot << 3) + (lane >> 3);
            const int su   = (lane & 7) ^ (r & 7);
            __builtin_amdgcn_global_load_lds(
                (glb_uint*)(Vg + (long)(j * 128 + r) * 2048 + c * 128 + (su << 4)),
                (lds_uint*)(base + (slot << 10)), 16, 0, 0);
        }
    };

    f32x4 U[2][4] = {};
    float m_run[2][4], l_run[2][4], alpha[2][4];
#pragma unroll
    for (int a = 0; a < 2; ++a)
#pragma unroll
        for (int b = 0; b < 4; ++b) { m_run[a][b] = -3.0e38f; l_run[a][b] = 0.0f; }

    stageQ();
    stageK(0, 0);

    for (int c = 0; c < 16; ++c) {
        f32x4 sacc[2] = {};
        // ---- S: 4 k-steps, 1 barrier each; staging AFTER the barrier ----
#pragma unroll
        for (int ks = 0; ks < 4; ++ks) {
            if (ks == 0) { if (c == 0) asm volatile("s_waitcnt vmcnt(0)" ::: "memory"); }
            else if (ks == 1) asm volatile("s_waitcnt vmcnt(2)" ::: "memory");
            else              asm volatile("s_waitcnt vmcnt(0)" ::: "memory");
            asm volatile("s_barrier" ::: "memory");
            if (ks == 0) { stageK(c, 1); stageV(c, 0); }
            else if (ks == 1) stageK(c, 2);
            else if (ks == 2) stageK(c, 3);
            else { stageV(c, 1); if (c + 1 < 16) stageK(c + 1, 0); }

            const unsigned char* Kb = (ks & 1) ? Ks1 : Ks0;
            F8 aq[2], bk;
#pragma unroll
            for (int fi = 0; fi < 2; ++fi) {
                const int l = fi * 16 + m16;
                aq[fi].q[0] = *(const int4*)&Qs[l * 512 + ks * 128 + offLo];
                aq[fi].q[1] = *(const int4*)&Qs[l * 512 + ks * 128 + offHi];
            }
            const int m = wave * 16 + m16;
            bk.q[0] = *(const int4*)&Kb[(m << 7) + offLo];
            bk.q[1] = *(const int4*)&Kb[(m << 7) + offHi];
            __builtin_amdgcn_s_setprio(1);
#pragma unroll
            for (int fi = 0; fi < 2; ++fi)
                sacc[fi] = __builtin_amdgcn_mfma_scale_f32_16x16x128_f8f6f4(
                    aq[fi].v, bk.v, sacc[fi], 0, 0, 0, 127, 0, 127);
            __builtin_amdgcn_s_setprio(0);
        }
        asm volatile("s_barrier" ::: "memory");   // post-S: all tile-3 reads retired

        // ---- softmax part 1: wave-local max (16 cols), cross-wave via sx ----
        float cm[2][4];
#pragma unroll
        for (int fi = 0; fi < 2; ++fi)
#pragma unroll
            for (int r = 0; r < 4; ++r) {
                float v = sacc[fi][r];
#pragma unroll
                for (int off = 1; off < 16; off <<= 1) v = fmaxf(v, __shfl_xor(v, off));
                cm[fi][r] = v;
            }
        if (m16 == 0) {
#pragma unroll
            for (int fi = 0; fi < 2; ++fi)
#pragma unroll
                for (int r = 0; r < 4; ++r)
                    sx[(fi * 16 + quad * 4 + r) * 8 + wave] = cm[fi][r];
        }
        asm volatile("s_waitcnt lgkmcnt(0)" ::: "memory");
        asm volatile("s_barrier" ::: "memory");

        // ---- softmax part 2: cm, T13 skip, p, sums, P publish ----
        bool grow = false;
#pragma unroll
        for (int fi = 0; fi < 2; ++fi)
#pragma unroll
            for (int r = 0; r < 4; ++r) {
                const int rr = fi * 16 + quad * 4 + r;
                float m1 = fmaxf(fmaxf(sx[rr * 8 + 0], sx[rr * 8 + 1]),
                                 fmaxf(sx[rr * 8 + 2], sx[rr * 8 + 3]));
                float m2 = fmaxf(fmaxf(sx[rr * 8 + 4], sx[rr * 8 + 5]),
                                 fmaxf(sx[rr * 8 + 6], sx[rr * 8 + 7]));
                cm[fi][r] = fmaxf(m1, m2);
                grow |= (cm[fi][r] > m_run[fi][r]);
            }
        if (__ballot(grow)) {
#pragma unroll
            for (int fi = 0; fi < 2; ++fi)
#pragma unroll
                for (int r = 0; r < 4; ++r) {
                    const float mn = fmaxf(m_run[fi][r], cm[fi][r]);
                    alpha[fi][r] = __expf(m_run[fi][r] - mn);
                    m_run[fi][r] = mn;
                }
#pragma unroll
            for (int fi = 0; fi < 2; ++fi)
#pragma unroll
                for (int j = 0; j < 4; ++j)
#pragma unroll
                    for (int r = 0; r < 4; ++r)
                        U[fi][j][r] *= alpha[fi][r];
        } else {
#pragma unroll
            for (int fi = 0; fi < 2; ++fi)
#pragma unroll
                for (int r = 0; r < 4; ++r) alpha[fi][r] = 1.0f;
        }
        float p[2][4];
#pragma unroll
        for (int fi = 0; fi < 2; ++fi)
#pragma unroll
            for (int r = 0; r < 4; ++r) {
                p[fi][r] = __expf(sacc[fi][r] - m_run[fi][r]);
                float v = p[fi][r];
#pragma unroll
                for (int off = 1; off < 16; off <<= 1) v += __shfl_xor(v, off);
                if (m16 == 0) sy[(fi * 16 + quad * 4 + r) * 8 + wave] = v;
            }
#pragma unroll
        for (int fi = 0; fi < 2; ++fi)
#pragma unroll
            for (int r = 0; r < 4; ++r) {
                const int l = fi * 16 + quad * 4 + r;
                Ps[(l << 7) + ((wave ^ (l & 7)) << 4) + m16] = f2fp8(p[fi][r] * 256.0f);
            }
        asm volatile("s_waitcnt lgkmcnt(0)" ::: "memory");
        asm volatile("s_barrier" ::: "memory");   // B: P/sy visible (Vq0 drained at ks2)

#pragma unroll
        for (int fi = 0; fi < 2; ++fi)
#pragma unroll
            for (int r = 0; r < 4; ++r) {
                const int rr = fi * 16 + quad * 4 + r;
                float s = ((sy[rr * 8 + 0] + sy[rr * 8 + 1]) + (sy[rr * 8 + 2] + sy[rr * 8 + 3]))
                        + ((sy[rr * 8 + 4] + sy[rr * 8 + 5]) + (sy[rr * 8 + 6] + sy[rr * 8 + 7]));
                l_run[fi][r] = l_run[fi][r] * alpha[fi][r] + s;
            }
        F8 pa[2];
#pragma unroll
        for (int fi = 0; fi < 2; ++fi) {
            const int l = fi * 16 + m16;
            pa[fi].q[0] = *(const int4*)&Ps[(l << 7) + offLo];
            pa[fi].q[1] = *(const int4*)&Ps[(l << 7) + offHi];
        }
        const int hl = wave * 16 + m16;
        // ---- quarter 0 (Vs0) ----
        {
            F8 vb;
            vb.q[0] = *(const int4*)&Vs0[(hl << 7) + offLo];
            vb.q[1] = *(const int4*)&Vs0[(hl << 7) + offHi];
            __builtin_amdgcn_s_setprio(1);
#pragma unroll
            for (int fi = 0; fi < 2; ++fi)
                U[fi][0] = __builtin_amdgcn_mfma_scale_f32_16x16x128_f8f6f4(
                    pa[fi].v, vb.v, U[fi][0], 0, 0, 0, 127, 0, 127);
            __builtin_amdgcn_s_setprio(0);
        }
        // ---- pre-q1: wait Vq1; barrier (q0 reads retired); stage Vq2 ----
        if (c + 1 < 16) asm volatile("s_waitcnt vmcnt(2)" ::: "memory");
        else            asm volatile("s_waitcnt vmcnt(0)" ::: "memory");
        asm volatile("s_barrier" ::: "memory");
        stageV(c, 2);
        {
            F8 vb;
            vb.q[0] = *(const int4*)&Vs1[(hl << 7) + offLo];
            vb.q[1] = *(const int4*)&Vs1[(hl << 7) + offHi];
            __builtin_amdgcn_s_setprio(1);
#pragma unroll
            for (int fi = 0; fi < 2; ++fi)
                U[fi][1] = __builtin_amdgcn_mfma_scale_f32_16x16x128_f8f6f4(
                    pa[fi].v, vb.v, U[fi][1], 0, 0, 0, 127, 0, 127);
            __builtin_amdgcn_s_setprio(0);
        }
        // ---- pre-q2: wait Vq2 (drains Kt0'); barrier; stage Vq3 ----
        asm volatile("s_waitcnt vmcnt(0)" ::: "memory");
        asm volatile("s_barrier" ::: "memory");
        stageV(c, 3);
        {
            F8 vb;
            vb.q[0] = *(const int4*)&Vs0[(hl << 7) + offLo];
            vb.q[1] = *(const int4*)&Vs0[(hl << 7) + offHi];
            __builtin_amdgcn_s_setprio(1);
#pragma unroll
            for (int fi = 0; fi < 2; ++fi)
                U[fi][2] = __builtin_amdgcn_mfma_scale_f32_16x16x128_f8f6f4(
                    pa[fi].v, vb.v, U[fi][2], 0, 0, 0, 127, 0, 127);
            __builtin_amdgcn_s_setprio(0);
        }
        // ---- pre-q3: wait Vq3; barrier ----
        asm volatile("s_waitcnt vmcnt(0)" ::: "memory");
        asm volatile("s_barrier" ::: "memory");
        {
            F8 vb;
            vb.q[0] = *(const int4*)&Vs1[(hl << 7) + offLo];
            vb.q[1] = *(const int4*)&Vs1[(hl << 7) + offHi];
            __builtin_amdgcn_s_setprio(1);
#pragma unroll
            for (int fi = 0; fi < 2; ++fi)
                U[fi][3] = __builtin_amdgcn_mfma_scale_f32_16x16x128_f8f6f4(
                    pa[fi].v, vb.v, U[fi][3], 0, 0, 0, 127, 0, 127);
            __builtin_amdgcn_s_setprio(0);
        }
    }

    // ---- epilogue: normalize, fp8 store ----
#pragma unroll
    for (int fi = 0; fi < 2; ++fi)
#pragma unroll
        for (int r = 0; r < 4; ++r) {
            const float inv = 1.0f / (256.0f * l_run[fi][r]);
            const long row = (long)z * 2048 + l0 + fi * 16 + quad * 4 + r;
#pragma unroll
            for (int j = 0; j < 4; ++j) {
                const int h = j * 128 + wave * 16 + m16;
                out8[row * 512 + h] = f2fp8(U[fi][j][r] * inv);
            }
        }
}

// ---------- launch ----------
extern "C" void kernel_launch(void* const* d_in, const int* in_sizes, int n_in,
                              void* d_out, int out_size, void* d_ws, size_t ws_size,
                              hipStream_t stream) {
    const float* x       = (const float*)d_in[0];
    const float* theta_w = (const float*)d_in[1];
    const float* theta_b = (const float*)d_in[2];
    const float* phi_w   = (const float*)d_in[3];
    const float* phi_b   = (const float*)d_in[4];
    const float* psi_w   = (const float*)d_in[5];
    const float* psi_b   = (const float*)d_in[6];
    const float* r1_w    = (const float*)d_in[7];
    const float* r1_b    = (const float*)d_in[8];
    const float* r2_w    = (const float*)d_in[9];
    const float* r2_b    = (const float*)d_in[10];
    float* out = (float*)d_out;

    constexpr int  N = 8, L = 2048, C = 512, H = 512, CH = 256;
    constexpr long NL = (long)N * L;  // 16384

    char* p = (char*)d_ws;
    auto alloc = [&](size_t bytes) { void* q = (void*)p; p += bytes; return q; };
    unsigned char*  xb8    = (unsigned char*)alloc(NL * C);            //  8 MB
    unsigned char*  TH8    = (unsigned char*)alloc(NL * H);            //  8 MB
    unsigned char*  PH8    = (unsigned char*)alloc(NL * H);            //  8 MB
    unsigned char*  VT8    = (unsigned char*)alloc((long)N * H * L);   //  8 MB
    unsigned char*  xadd8  = (unsigned char*)alloc(NL * H);            //  8 MB
    unsigned char*  h18    = (unsigned char*)alloc(NL * CH);           //  4 MB
    unsigned char*  wCat8T = (unsigned char*)alloc((long)1536 * 512);
    unsigned char*  r1T8   = (unsigned char*)alloc((long)H * CH);
    unsigned char*  r2T8   = (unsigned char*)alloc((long)CH * C);
    float*          bCat   = (float*)alloc(1536 * 4 + 256);

    // 1. prep
    prep<<<12294, 256, 0, stream>>>(x, theta_w, phi_w, psi_w, r1_w, r2_w,
                                    theta_b, phi_b, psi_b, xb8, wCat8T, r1T8, r2T8, bCat);

    // 2. merged fp8 projections -> TH8, PH8, VT8 (V^T via packed dword stores)
    gemm_fp8<0><<<dim3(NL / 128, 1536 / 128, 1), 256, 0, stream>>>(
        xb8, wCat8T, bCat, nullptr, TH8, PH8, VT8, nullptr,
        C, C, C, 0, 0, 0, 0);

    // 3-5. fused attention (32 q-rows/block, 2 blocks/CU, race-free schedule)
    flash<<<dim3(L / 32, N, 1), 512, 0, stream>>>(PH8, TH8, VT8, xadd8);

    // 6. h1 = leaky(x_add @ r1 + b) -> fp8
    gemm_fp8<3><<<dim3(NL / 128, CH / 128, 1), 256, 0, stream>>>(
        xadd8, r1T8, r1_b, nullptr, h18, nullptr, nullptr, nullptr,
        H, H, H, CH, 0, 0, 0);

    // 7. out = x + tanh(h1 @ r2 + b) -> fp32
    gemm_fp8<4><<<dim3(NL / 128, C / 128, 1), 256, 0, stream>>>(
        h18, r2T8, r2_b, x, nullptr, nullptr, nullptr, out,
        CH, CH, CH, C, 0, 0, 0);
}

// Round 9
// 220.654 us; speedup vs baseline: 2.6503x; 1.6601x over previous
//
#include <hip/hip_runtime.h>
#include <hip/hip_bf16.h>

// ---------- types ----------
typedef float f32x4 __attribute__((ext_vector_type(4)));
typedef int   v8i   __attribute__((ext_vector_type(8)));
typedef __attribute__((address_space(3))) unsigned int       lds_uint;
typedef __attribute__((address_space(1))) const unsigned int glb_uint;

// ---------- helpers ----------
__device__ __forceinline__ float tanh_fast(float x) {
    float e = __expf(-2.0f * fabsf(x));
    float r = (1.0f - e) / (1.0f + e);
    return copysignf(r, x);
}
__device__ __forceinline__ unsigned char f2fp8(float v) {
    return (unsigned char)(__builtin_amdgcn_cvt_pk_fp8_f32(v, 0.0f, 0, false) & 0xff);
}
__device__ __forceinline__ unsigned short f2h(float v) {
    _Float16 h = (_Float16)v;
    unsigned short u;
    __builtin_memcpy(&u, &h, 2);
    return u;
}
__device__ __forceinline__ float h2f(unsigned short u) {
    _Float16 h;
    __builtin_memcpy(&h, &u, 2);
    return (float)h;
}

// ---------- prep: x->fp8; proj W ->fp8(x16) T; r1/r2 ->fp8(x16) T; bias concat ----------
__global__ __launch_bounds__(256) void prep(
    const float* __restrict__ x,
    const float* __restrict__ theta_w, const float* __restrict__ phi_w,
    const float* __restrict__ psi_w,   const float* __restrict__ r1_w,
    const float* __restrict__ r2_w,
    const float* __restrict__ theta_b, const float* __restrict__ phi_b,
    const float* __restrict__ psi_b,
    unsigned char* __restrict__ xb8, unsigned char* __restrict__ wCat8T,
    unsigned char* __restrict__ r1T8, unsigned char* __restrict__ r2T8,
    float* __restrict__ bCat) {
    const int b = blockIdx.x, t = threadIdx.x;
    if (b < 8192) {                       // cast x -> fp8
        long i = ((long)b * 256 + t) * 4;
        float4 f = *(const float4*)(x + i);
        int w = __builtin_amdgcn_cvt_pk_fp8_f32(f.x, f.y, 0, false);
        w = __builtin_amdgcn_cvt_pk_fp8_f32(f.z, f.w, w, true);
        *(unsigned int*)(xb8 + i) = (unsigned int)w;
    } else if (b < 11264) {               // proj weights (512x512 each), x16, transposed
        const int sel = (b - 8192) >> 10;
        const int idx = ((b - 8192) & 1023) * 256 + t;
        const float* w = sel == 0 ? theta_w : (sel == 1 ? phi_w : psi_w);
        const int r = idx >> 9, c = idx & 511;
        wCat8T[(long)(sel * 512 + c) * 512 + r] = f2fp8(w[idx] * 16.0f);
    } else if (b < 11776) {               // r1 (512x256) -> fp8 x16 T
        const int idx = (b - 11264) * 256 + t;
        const int r = idx >> 8, c = idx & 255;
        r1T8[(long)c * 512 + r] = f2fp8(r1_w[idx] * 16.0f);
    } else if (b < 12288) {               // r2 (256x512) -> fp8 x16 T
        const int idx = (b - 11776) * 256 + t;
        const int r = idx >> 9, c = idx & 511;
        r2T8[(long)c * 256 + r] = f2fp8(r2_w[idx] * 16.0f);
    } else {                              // bias concat (1536)
        const int i = (b - 12288) * 256 + t;
        if (i < 1536)
            bCat[i] = i < 512 ? theta_b[i] : (i < 1024 ? phi_b[i - 512] : psi_b[i - 1024]);
    }
}

// ---------- row softmax: read fp16 S row, write fp8 P in-place (first half of row) ----------
__global__ __launch_bounds__(256) void softmax_fp8(unsigned short* __restrict__ S) {
    const size_t row = (size_t)blockIdx.y * 2048 + blockIdx.x;
    unsigned short* p = S + row * 2048;
    const int t = threadIdx.x;
    uint4 raw = *(uint4*)(p + t * 8);
    unsigned int w[4] = {raw.x, raw.y, raw.z, raw.w};
    float v[8];
#pragma unroll
    for (int i = 0; i < 4; ++i) {
        v[2 * i]     = h2f((unsigned short)(w[i] & 0xffffu));
        v[2 * i + 1] = h2f((unsigned short)(w[i] >> 16));
    }
    float mx = v[0];
#pragma unroll
    for (int i = 1; i < 8; ++i) mx = fmaxf(mx, v[i]);
#pragma unroll
    for (int off = 32; off > 0; off >>= 1) mx = fmaxf(mx, __shfl_xor(mx, off));
    __shared__ float red[8];
    const int wave = t >> 6, lane = t & 63;
    if (lane == 0) red[wave] = mx;
    __syncthreads();
    mx = fmaxf(fmaxf(red[0], red[1]), fmaxf(red[2], red[3]));
    float s = 0.0f;
#pragma unroll
    for (int i = 0; i < 8; ++i) { v[i] = __expf(v[i] - mx); s += v[i]; }
#pragma unroll
    for (int off = 32; off > 0; off >>= 1) s += __shfl_xor(s, off);
    if (lane == 0) red[4 + wave] = s;
    __syncthreads();
    s = red[4] + red[5] + red[6] + red[7];
    const float inv = 1.0f / s;
    int o0 = __builtin_amdgcn_cvt_pk_fp8_f32(v[0] * inv, v[1] * inv, 0, false);
    o0 = __builtin_amdgcn_cvt_pk_fp8_f32(v[2] * inv, v[3] * inv, o0, true);
    int o1 = __builtin_amdgcn_cvt_pk_fp8_f32(v[4] * inv, v[5] * inv, 0, false);
    o1 = __builtin_amdgcn_cvt_pk_fp8_f32(v[6] * inv, v[7] * inv, o1, true);
    uint2 ov; ov.x = (unsigned int)o0; ov.y = (unsigned int)o1;
    *(uint2*)((unsigned char*)p + t * 8) = ov;   // after barrier 2; reads were before barrier 1
}

// ---------- fp8 GEMM: 128x128 tile, BK=128, dbuf counted-vmcnt ----------
// MODE 1/2 use a 1-D grid with XCD-pinned decode: z = bid & 7 -> all blocks of a
// batch land on one XCD (empirical bid%8=XCD), making the batch's staged panels
// L2-resident (qkt: TH8+PH8 per z = 2 MB < 4 MB L2; pv: P 4MB + V 1MB ~resident).
// Within an XCD: panel-sharing blocks are consecutive in t for temporal reuse.
// MODE 0 proj:  v=acc/16+bCat[col]; col<1024 -> fp8 TH8/PH8 (pitch 512);
//               col>=1024 -> V^T (dword stores: 4 l-consecutive rows packed)
// MODE 1 qkt:   fp16 -> outH, ldc elems (grid 2048 1-D: z=bid&7, by=t&15, bx=t>>4)
// MODE 2 pv:    fp8  -> out8, pitch 512 (grid 512 1-D: z=bid&7, by=t&3, bx=t>>2)
// MODE 3 r1:    v=acc/16+bias; leaky 0.2; fp8 -> out8, pitch 256
// MODE 4 r2:    v=acc/16+bias; tanh; +resid; fp32 -> outF, ldc 512
template <int MODE>
__global__ __launch_bounds__(256) void gemm_fp8(
    const unsigned char* __restrict__ A,
    const unsigned char* __restrict__ Bt,
    const float* __restrict__ bias,
    const float* __restrict__ resid,
    unsigned short* __restrict__ outH,
    unsigned char* __restrict__ out8,
    unsigned char* __restrict__ out8b,
    unsigned char* __restrict__ outV,
    float* __restrict__ outF,
    int K, int ldaB, int ldbB, int ldc, long sA, long sB, long sC) {
    __shared__ unsigned char As[2][128 * 128];
    __shared__ unsigned char Bs[2][128 * 128];

    const int tid  = threadIdx.x;
    const int lane = tid & 63, wave = tid >> 6;
    const int m16  = lane & 15, quad = lane >> 4;
    const int wm   = (wave >> 1) << 6, wn = (wave & 1) << 6;

    int bx, by, z;
    if constexpr (MODE == 1) {            // qkt: XCD-pinned batch
        z = blockIdx.x & 7;
        const int t = blockIdx.x >> 3;    // 0..255 per XCD, in dispatch order
        by = t & 15; bx = t >> 4;         // A panel (bx) hot across 16 consecutive t
    } else if constexpr (MODE == 2) {     // pv: XCD-pinned batch
        z = blockIdx.x & 7;
        const int t = blockIdx.x >> 3;    // 0..63 per XCD
        by = t & 3;  bx = t >> 2;         // A panel (bx) hot across 4 consecutive t
    } else {
        bx = blockIdx.x; by = blockIdx.y; z = 0;
    }
    const int m0 = bx << 7, n0 = by << 7;

    const int srow = lane >> 3;
    const int uswz = (lane & 7) ^ srow;

    const unsigned char* Abase = A  + (long)z * sA + (long)m0 * ldaB;
    const unsigned char* Bbase = Bt + (long)z * sB + (long)n0 * ldbB;
    const int stR = (wave << 5) + srow;
    const long gA0 = (long)stR * ldaB + (uswz << 4);
    const long gB0 = (long)stR * ldbB + (uswz << 4);

    // LDS 16B-unit u of row m holds true unit u^(m&7); lane's 32B at region
    // P = quad^((m&7)>>1), half order flips w/ m&1 -> 2x ds_read_b128, bank-optimal.
    const int s8  = m16 & 7;
    const int P   = quad ^ (s8 >> 1);
    const int cLo = (P << 1) + (s8 & 1);
    const int offLo = cLo << 4;
    const int offHi = (cLo ^ 1) << 4;

    f32x4 acc[4][4] = {};
    union F8 { v8i v; int4 q[2]; };

    auto STAGE = [&](int buf, int kk) {
#pragma unroll
        for (int i = 0; i < 4; ++i) {
            const unsigned char* gp = Abase + gA0 + (long)(i << 3) * ldaB + kk;
            unsigned char* lp = &As[buf][((wave << 5) + (i << 3)) << 7];
            __builtin_amdgcn_global_load_lds((glb_uint*)gp, (lds_uint*)lp, 16, 0, 0);
        }
#pragma unroll
        for (int i = 0; i < 4; ++i) {
            const unsigned char* gp = Bbase + gB0 + (long)(i << 3) * ldbB + kk;
            unsigned char* lp = &Bs[buf][((wave << 5) + (i << 3)) << 7];
            __builtin_amdgcn_global_load_lds((glb_uint*)gp, (lds_uint*)lp, 16, 0, 0);
        }
    };

    STAGE(0, 0);
    int cur = 0;
    for (int k0 = 0; k0 < K; k0 += 128) {
        if (k0 + 128 < K) {
            STAGE(cur ^ 1, k0 + 128);
            asm volatile("s_waitcnt vmcnt(8)" ::: "memory");
        } else {
            asm volatile("s_waitcnt vmcnt(0)" ::: "memory");
        }
        asm volatile("s_barrier" ::: "memory");

        const unsigned char* Ab = As[cur];
        const unsigned char* Bb = Bs[cur];
        F8 af[4], bg[4];
#pragma unroll
        for (int f = 0; f < 4; ++f) {
            const int m = wm + (f << 4) + m16;
            const int n = wn + (f << 4) + m16;
            af[f].q[0] = *(const int4*)&Ab[(m << 7) + offLo];
            af[f].q[1] = *(const int4*)&Ab[(m << 7) + offHi];
            bg[f].q[0] = *(const int4*)&Bb[(n << 7) + offLo];
            bg[f].q[1] = *(const int4*)&Bb[(n << 7) + offHi];
        }
#pragma unroll
        for (int fi = 0; fi < 4; ++fi)
#pragma unroll
            for (int fj = 0; fj < 4; ++fj)
                acc[fi][fj] = __builtin_amdgcn_mfma_scale_f32_16x16x128_f8f6f4(
                    af[fi].v, bg[fj].v, acc[fi][fj],
                    0, 0, 0, 127, 0, 127);

        asm volatile("s_waitcnt lgkmcnt(0)" ::: "memory");
        asm volatile("s_barrier" ::: "memory");
        cur ^= 1;
    }

    const long zC = (long)z * sC;

    if (MODE == 0) {
        const int sel = n0 >> 9;                         // block-uniform
        if (sel < 2) {
            unsigned char* dst = sel == 0 ? out8 : out8b;
#pragma unroll
            for (int fj = 0; fj < 4; ++fj) {
                const int col = n0 + wn + (fj << 4) + m16;
                const int cb  = col & 511;
                const float bv = bias[col];
#pragma unroll
                for (int fi = 0; fi < 4; ++fi)
#pragma unroll
                    for (int r = 0; r < 4; ++r) {
                        const int row = m0 + wm + (fi << 4) + (quad << 2) + r;
                        dst[(long)row * 512 + cb] = f2fp8(acc[fi][fj][r] * 0.0625f + bv);
                    }
            }
        } else {                                         // V^T: pack 4 l-rows per dword
            const int zz = m0 >> 11, l0 = (m0 & 2047) + wm + (quad << 2);
#pragma unroll
            for (int fj = 0; fj < 4; ++fj) {
                const int col = n0 + wn + (fj << 4) + m16;
                const int h   = col & 511;
                const float bv = bias[col];
#pragma unroll
                for (int fi = 0; fi < 4; ++fi) {
                    int w = __builtin_amdgcn_cvt_pk_fp8_f32(
                        acc[fi][fj][0] * 0.0625f + bv, acc[fi][fj][1] * 0.0625f + bv, 0, false);
                    w = __builtin_amdgcn_cvt_pk_fp8_f32(
                        acc[fi][fj][2] * 0.0625f + bv, acc[fi][fj][3] * 0.0625f + bv, w, true);
                    *(unsigned int*)(outV + ((long)zz * 512 + h) * 2048 + l0 + (fi << 4)) =
                        (unsigned int)w;
                }
            }
        }
    } else {
#pragma unroll
        for (int fj = 0; fj < 4; ++fj) {
            const int col = n0 + wn + (fj << 4) + m16;
            float bv = 0.0f;
            if (MODE >= 3) bv = bias[col];
#pragma unroll
            for (int fi = 0; fi < 4; ++fi)
#pragma unroll
                for (int r = 0; r < 4; ++r) {
                    const int row = m0 + wm + (fi << 4) + (quad << 2) + r;
                    float v = acc[fi][fj][r];
                    if (MODE == 1) {
                        outH[zC + (long)row * ldc + col] = f2h(v);
                    } else if (MODE == 2) {
                        out8[zC + (long)row * 512 + col] = f2fp8(v);
                    } else if (MODE == 3) {
                        v = v * 0.0625f + bv;
                        v = v > 0.0f ? v : 0.2f * v;
                        out8[(long)row * 256 + col] = f2fp8(v);
                    } else {
                        v = v * 0.0625f + bv;
                        const long idx = (long)row * ldc + col;
                        outF[idx] = tanh_fast(v) + resid[idx];
                    }
                }
        }
    }
}

// ---------- launch ----------
extern "C" void kernel_launch(void* const* d_in, const int* in_sizes, int n_in,
                              void* d_out, int out_size, void* d_ws, size_t ws_size,
                              hipStream_t stream) {
    const float* x       = (const float*)d_in[0];
    const float* theta_w = (const float*)d_in[1];
    const float* theta_b = (const float*)d_in[2];
    const float* phi_w   = (const float*)d_in[3];
    const float* phi_b   = (const float*)d_in[4];
    const float* psi_w   = (const float*)d_in[5];
    const float* psi_b   = (const float*)d_in[6];
    const float* r1_w    = (const float*)d_in[7];
    const float* r1_b    = (const float*)d_in[8];
    const float* r2_w    = (const float*)d_in[9];
    const float* r2_b    = (const float*)d_in[10];
    float* out = (float*)d_out;

    constexpr int  N = 8, L = 2048, C = 512, H = 512, CH = 256;
    constexpr long NL = (long)N * L;  // 16384

    char* p = (char*)d_ws;
    auto alloc = [&](size_t bytes) { void* q = (void*)p; p += bytes; return q; };
    unsigned char*  xb8    = (unsigned char*)alloc(NL * C);            //  8 MB
    unsigned char*  TH8    = (unsigned char*)alloc(NL * H);            //  8 MB
    unsigned char*  PH8    = (unsigned char*)alloc(NL * H);            //  8 MB
    unsigned char*  VT8    = (unsigned char*)alloc((long)N * H * L);   //  8 MB
    unsigned char*  xadd8  = (unsigned char*)alloc(NL * H);            //  8 MB
    unsigned char*  h18    = (unsigned char*)alloc(NL * CH);           //  4 MB
    unsigned char*  wCat8T = (unsigned char*)alloc((long)1536 * 512);
    unsigned char*  r1T8   = (unsigned char*)alloc((long)H * CH);
    unsigned char*  r2T8   = (unsigned char*)alloc((long)CH * C);
    float*          bCat   = (float*)alloc(1536 * 4 + 256);
    unsigned short* S      = (unsigned short*)alloc((long)N * L * L * 2);  // 64 MB fp16/P-fp8

    // 1. prep
    prep<<<12294, 256, 0, stream>>>(x, theta_w, phi_w, psi_w, r1_w, r2_w,
                                    theta_b, phi_b, psi_b, xb8, wCat8T, r1T8, r2T8, bCat);

    // 2. merged fp8 projections -> TH8, PH8, VT8 (V^T via packed dword stores)
    gemm_fp8<0><<<dim3(NL / 128, 1536 / 128, 1), 256, 0, stream>>>(
        xb8, wCat8T, bCat, nullptr, nullptr, TH8, PH8, VT8, nullptr,
        C, C, C, 0, 0, 0, 0);

    // 3. S = phi @ theta^T (fp8 in, fp16 out) — 1-D grid, z = bid&7 pins batch->XCD
    gemm_fp8<1><<<dim3((L / 128) * (L / 128) * N, 1, 1), 256, 0, stream>>>(
        PH8, TH8, nullptr, nullptr, S, nullptr, nullptr, nullptr, nullptr,
        H, H, H, L, (long)L * H, (long)L * H, (long)L * L);

    // 4. softmax rows, fp16 -> fp8 in place
    softmax_fp8<<<dim3(L, N), 256, 0, stream>>>(S);

    // 5. x_add = P @ V (fp8; P rows at 4096-B pitch, V^T rows at 2048-B pitch) -> fp8
    gemm_fp8<2><<<dim3((L / 128) * (H / 128) * N, 1, 1), 256, 0, stream>>>(
        (const unsigned char*)S, VT8, nullptr, nullptr, nullptr, xadd8, nullptr, nullptr, nullptr,
        L, 2 * L, L, H, (long)L * 2 * L, (long)H * L, (long)L * H);

    // 6. h1 = leaky(x_add @ r1 + b) -> fp8
    gemm_fp8<3><<<dim3(NL / 128, CH / 128, 1), 256, 0, stream>>>(
        xadd8, r1T8, r1_b, nullptr, nullptr, h18, nullptr, nullptr, nullptr,
        H, H, H, CH, 0, 0, 0);

    // 7. out = x + tanh(h1 @ r2 + b) -> fp32
    gemm_fp8<4><<<dim3(NL / 128, C / 128, 1), 256, 0, stream>>>(
        h18, r2T8, r2_b, x, nullptr, nullptr, nullptr, nullptr, out,
        CH, CH, CH, C, 0, 0, 0);
}